// Round 16
// baseline (355.796 us; speedup 1.0000x reference)
//
#include <hip/hip_runtime.h>
#include <stdint.h>

#define DIM   2048
#define NSLOT 64
#define MDIM  512
#define TINV  10.0f

typedef __attribute__((ext_vector_type(4))) float     f32x4;
typedef __attribute__((ext_vector_type(8))) _Float16  half8;

#define MFMA16(a,b,c) __builtin_amdgcn_mfma_f32_16x16x32_f16((a),(b),(c),0,0,0)
#define AS1 __attribute__((address_space(1)))
#define AS3 __attribute__((address_space(3)))

// ---------------------------------------------------------------------------
// ws layout (bytes) — IDENTICAL to round 15 (prep validated):
//   W2F  [32ch] x 24576 B — fragment-packed W2, K=64 chunks, padded to 24 KB
//        (valid 20 KB: groups (t*2+ks)*2+lvl of 512 halfs; t=4 = gate tile,
//         now unused by the fused kernel but still written by prep)
//   W3T  [2048][64] f16
//   h    [64] f32
//   tpart[8][512] f32
// ---------------------------------------------------------------------------
#define OFF_W2F   0
#define OFF_W3T   1310720
#define OFF_H     1572864
#define OFF_TPART 1573120

__device__ __forceinline__ size_t w2f_idx(int row, int k, int lvl) {
    const int t  = row >> 4, ar = row & 15;
    const int ch = k >> 6, ks = (k >> 5) & 1, kg = (k >> 3) & 3, e = k & 7;
    return (size_t)ch * 12288 +
           ((size_t)(((t * 2 + ks) * 2 + lvl) * 64) + kg * 16 + ar) * 8 + e;
}

// ===================== merged prep kernel (w2 | w3t | t) ====================
// (byte-identical to round 15, validated)

__global__ __launch_bounds__(256) void prep_all(
    const float* __restrict__ memory, const float* __restrict__ key_w,
    const float* __restrict__ value_w, const float* __restrict__ gate_w,
    _Float16* __restrict__ W2F, _Float16* __restrict__ W3T,
    float* __restrict__ tpart)
{
    const int tid = threadIdx.x;
    const int c = blockIdx.x;
    const int role = blockIdx.y;

    if (role == 17) {                       // ---- prep_t ----
        const int b = c;
        float a0 = 0.f, a1 = 0.f;
        for (int d = b * 256; d < b * 256 + 256; ++d) {
            const float gv = gate_w[DIM + d];
            a0 = fmaf(value_w[(size_t)d * MDIM + tid], gv, a0);
            a1 = fmaf(value_w[(size_t)d * MDIM + tid + 256], gv, a1);
        }
        tpart[b * 512 + tid] = a0;
        tpart[b * 512 + tid + 256] = a1;
        return;
    }

    if (role < 9) {                         // ---- prep_w2 ----
        const int g = role;
        const int k = c * 256 + tid;
        if (g == 8) {
            float v = gate_w[k];
            _Float16 ph = (_Float16)v;
            _Float16 pl = (_Float16)(v - (float)ph);
            W2F[w2f_idx(64, k, 0)] = ph;
            W2F[w2f_idx(64, k, 1)] = pl;
            for (int r = 65; r < 80; ++r) {
                W2F[w2f_idx(r, k, 0)] = (_Float16)0.f;
                W2F[w2f_idx(r, k, 1)] = (_Float16)0.f;
            }
            return;
        }
        __shared__ __align__(16) float mem_s[8 * MDIM];
        for (int i = tid; i < 8 * MDIM; i += 256)
            mem_s[i] = memory[g * 8 * MDIM + i];
        __syncthreads();

        const f32x4* ms4 = (const f32x4*)mem_s;
        float acc[8] = {};
        for (int m4 = 0; m4 < MDIM / 4; ++m4) {
            const float kw0 = key_w[(size_t)(m4 * 4 + 0) * DIM + k];
            const float kw1 = key_w[(size_t)(m4 * 4 + 1) * DIM + k];
            const float kw2 = key_w[(size_t)(m4 * 4 + 2) * DIM + k];
            const float kw3 = key_w[(size_t)(m4 * 4 + 3) * DIM + k];
            #pragma unroll
            for (int i = 0; i < 8; ++i) {
                const f32x4 mv = ms4[i * (MDIM / 4) + m4];
                acc[i] = fmaf(mv.x, kw0, acc[i]);
                acc[i] = fmaf(mv.y, kw1, acc[i]);
                acc[i] = fmaf(mv.z, kw2, acc[i]);
                acc[i] = fmaf(mv.w, kw3, acc[i]);
            }
        }
        #pragma unroll
        for (int i = 0; i < 8; ++i) {
            float v = acc[i];
            _Float16 ph = (_Float16)v;
            _Float16 pl = (_Float16)(v - (float)ph);
            W2F[w2f_idx(g * 8 + i, k, 0)] = ph;
            W2F[w2f_idx(g * 8 + i, k, 1)] = pl;
        }
        return;
    }

    {                                       // ---- prep_w3t ----
        const int g = role - 9;
        const int d = c * 256 + tid;
        __shared__ __align__(16) float mem_s2[8 * MDIM];
        for (int i = tid; i < 8 * MDIM; i += 256)
            mem_s2[i] = memory[g * 8 * MDIM + i];
        __syncthreads();

        const f32x4* ms4 = (const f32x4*)mem_s2;
        const f32x4* vp = (const f32x4*)(value_w + (size_t)d * MDIM);
        float acc[8] = {};
        for (int m4 = 0; m4 < MDIM / 4; ++m4) {
            const f32x4 v = vp[m4];
            #pragma unroll
            for (int i = 0; i < 8; ++i) {
                const f32x4 mv = ms4[i * (MDIM / 4) + m4];
                acc[i] = fmaf(mv.x, v.x, acc[i]);
                acc[i] = fmaf(mv.y, v.y, acc[i]);
                acc[i] = fmaf(mv.z, v.z, acc[i]);
                acc[i] = fmaf(mv.w, v.w, acc[i]);
            }
        }
        #pragma unroll
        for (int i = 0; i < 8; ++i)
            W3T[(size_t)d * NSLOT + g * 8 + i] = (_Float16)acc[i];
    }
}

__global__ __launch_bounds__(512) void prep_h(
    const float* __restrict__ memory, const float* __restrict__ tpart,
    float* __restrict__ h)
{
    __shared__ float ts[512];
    const int tid = threadIdx.x;
    float s = 0.f;
    #pragma unroll
    for (int b = 0; b < 8; ++b) s += tpart[b * 512 + tid];
    ts[tid] = s;
    __syncthreads();
    const int lane = tid & 63, w = tid >> 6;
    #pragma unroll
    for (int q = 0; q < 8; ++q) {
        const int n = w * 8 + q;
        float p = 0.f;
        for (int m = lane; m < MDIM; m += 64)
            p = fmaf(memory[(size_t)n * MDIM + m], ts[m], p);
        #pragma unroll
        for (int off = 32; off; off >>= 1) p += __shfl_xor(p, off);
        if (lane == 0) h[n] = p;
    }
}

// ============================ fused kernel =================================
// LINEAR-HBM design. Block = 16 rows (one m-tile), 256 thr / 4 waves, grid
// 2048. x panel (16 rows x 8 KB = 128 KB) DMA'd to LDS in ROW-LINEAR order
// (8 KB contiguous bursts, XOR granule swizzle per rule #21); x is read from
// HBM exactly ONCE and out is written as 2 KB contiguous row segments.
//  - phase A: K-split 4 waves x 512 k; W2 fragments L2-direct (R10-validated
//    addressing) with 1-step rotation; gate g1-dot = fp32 VALU over panel.
//  - combine/softmax: R9-validated pattern (wave 0).
//  - phase B: R5-validated swapped-MFMA, per-wave d-quarter; mix x from
//    panel; out written into panel, flushed per wave (no barrier needed).

__global__ __launch_bounds__(256) void fused_kernel(
    const float* __restrict__ x,
    const _Float16* __restrict__ W2F,
    const _Float16* __restrict__ W3T,
    const float* __restrict__ h, const float* __restrict__ gate_w,
    const float* __restrict__ gate_b, float* __restrict__ out)
{
    __shared__ __align__(16) float panel[16 * 2048];      // 128 KB
    __shared__ __align__(16) float ppart[3 * 4 * 64 * 4]; // 12 KB
    __shared__ __align__(16) _Float16 attn_s[16][72];     // 2.25 KB
    __shared__ float xg[16];
    __shared__ float gate_s[16];

    const int tid  = threadIdx.x;
    const int lane = tid & 63;
    const int w    = tid >> 6;          // wave 0..3 = k-quarter / d-quarter
    const int ar   = lane & 15;
    const int kg   = lane >> 4;
    const size_t row0 = (size_t)blockIdx.x * 16;

    // ---- 1. panel DMA: row-linear, source granule XOR-swizzled ----
    // physical granule (row, q) holds logical (row, q ^ (row&7))
    #pragma unroll
    for (int i = 0; i < 32; ++i) {
        const int g   = i * 256 + tid;
        const int row = g >> 9, q = g & 511;
        const int lq  = q ^ (row & 7);
        const char* src = (const char*)x + (row0 + row) * 8192 + (size_t)lq * 16;
        float* dst = panel + (size_t)(i * 256 + w * 64) * 4;   // wave-uniform base
        __builtin_amdgcn_global_load_lds((const AS1 void*)src, (AS3 void*)dst, 16, 0, 0);
    }
    asm volatile("s_waitcnt vmcnt(0)" ::: "memory");
    __builtin_amdgcn_s_barrier();

    // ---- 2. gate g1-dot (fp32 VALU): wave w covers rows w*4..w*4+3 ----
    #pragma unroll
    for (int rr = 0; rr < 4; ++rr) {
        const int r = w * 4 + rr;
        float a = 0.f;
        #pragma unroll
        for (int j = 0; j < 32; ++j) {
            const int d = j * 64 + lane;
            const float f = panel[r * 2048 + (((d >> 2) ^ (r & 7)) << 2) + (d & 3)];
            a = fmaf(f, gate_w[d], a);
        }
        #pragma unroll
        for (int off = 32; off; off >>= 1) a += __shfl_xor(a, off);
        if (lane == 0) xg[r] = a;
    }

    // ---- 3. scores: wave w covers k in [w*512, w*512+512), 16 k-steps ----
    f32x4 acc[4];
    {   f32x4 z = {0.f, 0.f, 0.f, 0.f};
        #pragma unroll
        for (int t = 0; t < 4; ++t) acc[t] = z; }

    const _Float16* w2base = W2F + lane * 8;
    auto frp = [&](int s, int t, int lvl) {
        const int ch  = w * 8 + (s >> 1);
        const int grp = (t * 2 + (s & 1)) * 2 + lvl;
        return (const half8*)(w2base + (size_t)ch * 12288 + grp * 512);
    };

    half8 fr[2][4][2];
    #pragma unroll
    for (int t = 0; t < 4; ++t) {
        fr[0][t][0] = *frp(0, t, 0);
        fr[0][t][1] = *frp(0, t, 1);
    }

    #pragma unroll
    for (int s = 0; s < 16; ++s) {
        const int cur = s & 1, nxt = cur ^ 1;
        if (s < 15) {
            #pragma unroll
            for (int t = 0; t < 4; ++t) {
                fr[nxt][t][0] = *frp(s + 1, t, 0);
                fr[nxt][t][1] = *frp(s + 1, t, 1);
            }
        }
        const int lq0 = w * 128 + s * 8 + kg * 2;
        const f32x4 xa = *(const f32x4*)(panel + ((size_t)ar * 512 + (lq0 ^ (ar & 7))) * 4);
        const f32x4 xb = *(const f32x4*)(panel + ((size_t)ar * 512 + ((lq0 + 1) ^ (ar & 7))) * 4);
        const float xf[8] = {xa.x, xa.y, xa.z, xa.w, xb.x, xb.y, xb.z, xb.w};
        _Float16 hh[8], ll[8];
        #pragma unroll
        for (int u = 0; u < 8; ++u) {
            hh[u] = (_Float16)xf[u];
            ll[u] = (_Float16)(xf[u] - (float)hh[u]);
        }
        const half8 ah = {hh[0], hh[1], hh[2], hh[3], hh[4], hh[5], hh[6], hh[7]};
        const half8 al = {ll[0], ll[1], ll[2], ll[3], ll[4], ll[5], ll[6], ll[7]};
        #pragma unroll
        for (int t = 0; t < 4; ++t) {
            acc[t] = MFMA16(ah, fr[cur][t][0], acc[t]);
            acc[t] = MFMA16(al, fr[cur][t][0], acc[t]);
            acc[t] = MFMA16(ah, fr[cur][t][1], acc[t]);
        }
    }

    // ---- 4. K-split combine + softmax + gate (wave 0) ----
    if (w > 0) {
        #pragma unroll
        for (int t = 0; t < 4; ++t)
            *(f32x4*)(ppart + (size_t)(((w - 1) * 4 + t) * 64 + lane) * 4) = acc[t];
    }
    __syncthreads();

    if (w == 0) {
        #pragma unroll
        for (int q = 0; q < 3; ++q)
            #pragma unroll
            for (int t = 0; t < 4; ++t)
                acc[t] += *(const f32x4*)(ppart + (size_t)((q * 4 + t) * 64 + lane) * 4);

        float hl[4];
        #pragma unroll
        for (int t = 0; t < 4; ++t) hl[t] = h[t * 16 + ar];
        const float gb = gate_b[0];

        #pragma unroll
        for (int j = 0; j < 4; ++j) {
            float m = fmaxf(fmaxf(acc[0][j], acc[1][j]), fmaxf(acc[2][j], acc[3][j]));
            #pragma unroll
            for (int off = 1; off < 16; off <<= 1) m = fmaxf(m, __shfl_xor(m, off));
            float p[4];
            float sum = 0.f;
            #pragma unroll
            for (int t = 0; t < 4; ++t) { p[t] = __expf((acc[t][j] - m) * TINV); sum += p[t]; }
            #pragma unroll
            for (int off = 1; off < 16; off <<= 1) sum += __shfl_xor(sum, off);
            const float inv = 1.f / sum;
            const int row = kg * 4 + j;
            float gp = 0.f;
            #pragma unroll
            for (int t = 0; t < 4; ++t) {
                const float a = p[t] * inv;
                attn_s[row][t * 16 + ar] = (_Float16)a;
                gp = fmaf(a, hl[t], gp);
            }
            #pragma unroll
            for (int off = 1; off < 16; off <<= 1) gp += __shfl_xor(gp, off);
            if (ar == 0)
                gate_s[row] = 1.f / (1.f + __expf(-(xg[row] + gp + gb)));
        }
    }
    __syncthreads();

    // ---- 5. phase B: wave w covers d in [w*512, w*512+512), 32 d-tiles ----
    const half8 a0 = *(const half8*)(&attn_s[ar][kg * 8]);
    const half8 a1 = *(const half8*)(&attn_s[ar][kg * 8 + 32]);
    const float g = gate_s[ar];
    const _Float16* w3base = W3T + (size_t)(w * 512 + ar) * NSLOT + kg * 8;

    half8 qb0[4], qb1[4];
    #pragma unroll
    for (int s = 0; s < 4; ++s) {
        const _Float16* bp = w3base + (size_t)s * 16 * NSLOT;
        qb0[s] = *(const half8*)bp;
        qb1[s] = *(const half8*)(bp + 32);
    }

    #pragma unroll 4
    for (int dt = 0; dt < 32; ++dt) {
        const int s = dt & 3;
        f32x4 r = {0.f, 0.f, 0.f, 0.f};
        r = MFMA16(qb0[s], a0, r);                  // swapped operands (validated)
        r = MFMA16(qb1[s], a1, r);
        int nt = dt + 4; if (nt > 31) nt = 31;      // clamped prefetch
        const _Float16* bp = w3base + (size_t)nt * 16 * NSLOT;
        qb0[s] = *(const half8*)bp;
        qb1[s] = *(const half8*)(bp + 32);
        // mix with x from panel; write result back into panel (own slot)
        const size_t pg = (size_t)ar * 512 + ((w * 128 + dt * 4 + kg) ^ (ar & 7));
        const f32x4 xv = *(const f32x4*)(panel + pg * 4);
        f32x4 o;
        o.x = fmaf(g, xv.x - r.x, r.x);
        o.y = fmaf(g, xv.y - r.y, r.y);
        o.z = fmaf(g, xv.z - r.z, r.z);
        o.w = fmaf(g, xv.w - r.w, r.w);
        *(f32x4*)(panel + pg * 4) = o;
    }

    // ---- 6. per-wave flush of its own d-range: 2 KB linear row segments ----
    asm volatile("s_waitcnt lgkmcnt(0)" ::: "memory");
    __builtin_amdgcn_sched_barrier(0);
    #pragma unroll
    for (int rr = 0; rr < 16; ++rr) {
        #pragma unroll
        for (int b = 0; b < 2; ++b) {
            const int lq = w * 128 + lane * 2 + b;
            const f32x4 v = *(const f32x4*)(panel + ((size_t)rr * 512 + (lq ^ (rr & 7))) * 4);
            *(f32x4*)((char*)out + (row0 + rr) * 8192 + (size_t)lq * 16) = v;
        }
    }
}

// ================================ launch ===================================

extern "C" void kernel_launch(void* const* d_in, const int* in_sizes, int n_in,
                              void* d_out, int out_size, void* d_ws, size_t ws_size,
                              hipStream_t stream) {
    (void)in_sizes; (void)n_in; (void)out_size; (void)ws_size;
    const float* x       = (const float*)d_in[0];
    const float* memory  = (const float*)d_in[1];
    const float* key_w   = (const float*)d_in[2];
    const float* value_w = (const float*)d_in[3];
    const float* gate_w  = (const float*)d_in[4];
    const float* gate_b  = (const float*)d_in[5];
    float* out = (float*)d_out;

    char* wsb = (char*)d_ws;                       // needs ~1.6 MB
    _Float16* W2F = (_Float16*)(wsb + OFF_W2F);
    _Float16* W3T = (_Float16*)(wsb + OFF_W3T);
    float*    h   = (float*)(wsb + OFF_H);
    float*    tpt = (float*)(wsb + OFF_TPART);

    prep_all<<<dim3(8, 18), 256, 0, stream>>>(memory, key_w, value_w, gate_w,
                                              W2F, W3T, tpt);
    prep_h  <<<1, 512, 0, stream>>>(memory, tpt, h);

    fused_kernel<<<2048, 256, 0, stream>>>(x, W2F, W3T, h, gate_w, gate_b, out);
}